// Round 9
// baseline (21778.264 us; speedup 1.0000x reference)
//
#include <hip/hip_runtime.h>
#include <stdint.h>

typedef unsigned long long u64;
typedef uint32_t u32;

#define NB     256
#define NT     256
#define TMAX   2048
#define EPROJS 1024
#define DUNITS 512
#define EMBED  512
#define JOINT  512
#define ODIM   10000

#define N_LSTM 32          // blocks 0..31: LSTM + replica-atomic u producers
#define CONS0  32          // blocks 32..254: consumers (W_out)
#define N_CONS 223
#define AGG_B  255         // block 255: score/token aggregator
#define MAGIC  0xD07ED07Eu

// workspace layout (bytes); first 57344 B zeroed by rnnt_init
// total = 57344 + 4 MB = 4,251,648 B (< r3-proven 4,358,144)
#define WS_PK   0          // u64[4][224]   consumer packs, 4-deep ring (tag bits 48+)
#define WS_SA   7168       // u64[4][224]   consumer sum-exp, 4-deep ring (tag bits 32+)
#define WS_DN   14336      // u32[256]      setup-done flags
#define WS_AGG  15360      // u32 aggregator-epoch replicas [8] @ 128B stride
#define WS_UD   16384      // u32 per-LSTM-block u-done tags, 32 @ 128B stride (4 KB)
#define WS_Y    20480      // u64[512]      tagged y words (epoch<<32 | f32)
#define WS_U    24576      // float[2][8][512] u replicas, parity-2 (32 KB)
#define WS_HP   57344      // float[2048][512] h_proj  (4 MB)

__device__ __forceinline__ float aloadf(const float* p){
  return __hip_atomic_load(p, __ATOMIC_RELAXED, __HIP_MEMORY_SCOPE_AGENT);
}
__device__ __forceinline__ void astoref(float* p, float v){
  __hip_atomic_store(p, v, __ATOMIC_RELAXED, __HIP_MEMORY_SCOPE_AGENT);
}
__device__ __forceinline__ u64 aloadu64(const u64* p){
  return __hip_atomic_load(p, __ATOMIC_RELAXED, __HIP_MEMORY_SCOPE_AGENT);
}
__device__ __forceinline__ void astoreu64(u64* p, u64 v){
  __hip_atomic_store(p, v, __ATOMIC_RELAXED, __HIP_MEMORY_SCOPE_AGENT);
}
__device__ __forceinline__ u32 aloadu32(const u32* p){
  return __hip_atomic_load(p, __ATOMIC_RELAXED, __HIP_MEMORY_SCOPE_AGENT);
}
__device__ __forceinline__ void astoreu32(u32* p, u32 v){
  __hip_atomic_store(p, v, __ATOMIC_RELAXED, __HIP_MEMORY_SCOPE_AGENT);
}

__device__ __forceinline__ u32 ordbits(float f){
  u32 u = __float_as_uint(f);
  return (u & 0x80000000u) ? ~u : (u | 0x80000000u);
}
__device__ __forceinline__ float unordbits(u32 o){
  u32 u = (o & 0x80000000u) ? (o & 0x7fffffffu) : ~o;
  return __uint_as_float(u);
}
__device__ __forceinline__ float sigmoidf_(float x){ return 1.0f/(1.0f+expf(-x)); }

__device__ __forceinline__ float wredsum(float v){
  #pragma unroll
  for (int o=32;o>0;o>>=1) v += __shfl_xor(v, o);
  return v;
}
__device__ __forceinline__ u64 wredmax64(u64 v){
  #pragma unroll
  for (int o=32;o>0;o>>=1){ u64 x = __shfl_xor(v, o); v = (x>v)?x:v; }
  return v;
}

// swizzled 512-float LDS stage: j -> (j&7)*64 + ((j>>3) ^ ((j&7)<<2))
// write (j=2tid,2tid+1): <=2-way alias (free); read j=8*lane+e: conflict-free.
__device__ __forceinline__ int zslot(int j){
  return (j&7)*64 + ((j>>3) ^ ((j&7)<<2));
}

#define LOAD8(dst, baseptr) { const float4* _p=(const float4*)(baseptr); \
  float4 _a=_p[0], _b=_p[1]; \
  dst[0]=_a.x; dst[1]=_a.y; dst[2]=_a.z; dst[3]=_a.w; \
  dst[4]=_b.x; dst[5]=_b.y; dst[6]=_b.z; dst[7]=_b.w; }

__global__ void rnnt_init(char* ws){
  // zero rings, flags, agg-epoch, u-done, tagged y, u replicas (57344 B = 14336 u32)
  u32* p = (u32*)ws;
  const int stride = blockDim.x * gridDim.x;
  for (int i = blockIdx.x*blockDim.x + threadIdx.x; i < 14336; i += stride) p[i] = 0u;
}

__global__ void __launch_bounds__(NT, 1)
rnnt_decode(const float* __restrict__ h,    const float* __restrict__ embed,
            const float* __restrict__ W_ih, const float* __restrict__ W_hh,
            const float* __restrict__ b_ih, const float* __restrict__ b_hh,
            const float* __restrict__ W_enc,const float* __restrict__ b_enc,
            const float* __restrict__ W_dec,const float* __restrict__ W_out,
            const float* __restrict__ b_out,
            float* __restrict__ out, char* __restrict__ ws)
{
  const int b    = blockIdx.x;
  const int tid  = threadIdx.x;
  const int lane = tid & 63;
  const int w    = tid >> 6;

  u64*   ytag = (u64*)(ws + WS_Y);
  float* ubuf = (float*)(ws + WS_U);      // [2][8][512]
  u64*  pkall = (u64*)(ws + WS_PK);
  u64*  saall = (u64*)(ws + WS_SA);
  u32*  done  = (u32*)(ws + WS_DN);
  u32*  aggr  = (u32*)(ws + WS_AGG);
  u32*  udone = (u32*)(ws + WS_UD);
  float* hp   = (float*)(ws + WS_HP);

  __shared__ float smem[8192];                 // 32 KB, multi-purpose
  float* GL = &smem[4416];                     // gates   (64)
  u64*   R64= (u64*)&smem[4480];               // 4 u64 reduce slots
  float* RF = &smem[4488];                     // 4 float reduce slots
  float* YO = &smem[4492];                     // fresh own-y (16)
  float* SL = &smem[4544];                     // swizzled 512-float stage (y or z)

  // ================= setup: hp = h @ W_enc^T + b_enc (rows 8b..8b+7) =========
  {
    float (*lds_h)[EPROJS] = (float(*)[EPROJS])smem;
    #pragma unroll
    for (int r=0;r<8;r++){
      const float4 hv = *(const float4*)(h + (size_t)(8*b + r)*EPROJS + tid*4);
      *(float4*)&lds_h[r][tid*4] = hv;
    }
    __syncthreads();
    for (int p=0;p<2;p++){
      const int j = p*NT + tid;
      float acc[8] = {0,0,0,0,0,0,0,0};
      const float4* wrow = (const float4*)(W_enc + (size_t)j*EPROJS);
      for (int k4=0;k4<EPROJS/4;k4++){
        const float4 wv = wrow[k4];
        #pragma unroll
        for (int t8=0;t8<8;t8++){
          const float4 hv = *(const float4*)&lds_h[t8][k4*4];
          acc[t8] = fmaf(wv.x,hv.x, fmaf(wv.y,hv.y, fmaf(wv.z,hv.z, fmaf(wv.w,hv.w, acc[t8]))));
        }
      }
      const float be = b_enc[j];
      #pragma unroll
      for (int t8=0;t8<8;t8++)
        astoref(&hp[(size_t)(8*b+t8)*JOINT + j], acc[t8] + be);
    }
    asm volatile("s_waitcnt vmcnt(0)" ::: "memory");
    if (tid==0) astoreu32(&done[b], MAGIC);
    __syncthreads();   // smem reuse fence
  }

  // ============================ role: LSTM ===================================
  if (b < N_LSTM){
    const int d = b;
    float wih[16][8], whh[16][8];
    #pragma unroll
    for (int q=0;q<16;q++){
      const int gr = w*DUNITS + 16*d + q;       // wave w = gate type (i,f,g,o)
      LOAD8(wih[q], W_ih + (size_t)gr*EMBED  + lane*8);
      LOAD8(whh[q], W_hh + (size_t)gr*DUNITS + lane*8);
    }
    // W_dec COLUMN slice: thread owns rows 2tid,2tid+1 x cols [16d,16d+16)
    float wdc0[16], wdc1[16];
    {
      const float4* p0 = (const float4*)(W_dec + (size_t)(2*tid)*DUNITS   + 16*d);
      const float4* p1 = (const float4*)(W_dec + (size_t)(2*tid+1)*DUNITS + 16*d);
      #pragma unroll
      for (int k4=0;k4<4;k4++){
        const float4 a = p0[k4];
        wdc0[4*k4+0]=a.x; wdc0[4*k4+1]=a.y; wdc0[4*k4+2]=a.z; wdc0[4*k4+3]=a.w;
        const float4 c = p1[k4];
        wdc1[4*k4+0]=c.x; wdc1[4*k4+1]=c.y; wdc1[4*k4+2]=c.z; wdc1[4*k4+3]=c.w;
      }
    }
    // per-lane gate bias: wave w, lane q<16 -> gate row w*DUNITS + 16d + q
    float bias_l = 0.0f;
    if (lane < 16){
      const int gr = w*DUNITS + 16*d + lane;
      bias_l = b_ih[gr] + b_hh[gr];
    }
    // bootstrap state -> publish tagged y(1) + replica-add u(1) (parity 1)
    float c_st = 0.0f, y_st = 0.0f;
    if (tid < 16){
      const int j = 16*d + tid;
      const float gi = b_ih[j]            + b_hh[j];
      const float gg = b_ih[2*DUNITS + j] + b_hh[2*DUNITS + j];
      const float go = b_ih[3*DUNITS + j] + b_hh[3*DUNITS + j];
      c_st = sigmoidf_(gi)*tanhf(gg);
      y_st = sigmoidf_(go)*tanhf(c_st);
      YO[tid] = y_st;
      astoreu64(&ytag[j], ((u64)1u<<32) | (u64)__float_as_uint(y_st));
    }
    __syncthreads();
    {
      float p0=0.f, p1=0.f;
      #pragma unroll
      for (int k=0;k<16;k++){ p0 = fmaf(wdc0[k], YO[k], p0); p1 = fmaf(wdc1[k], YO[k], p1); }
      float* up = ubuf + 1*4096 + (d&7)*512;    // parity 1, replica d&7
      atomicAdd(&up[2*tid],   p0);
      atomicAdd(&up[2*tid+1], p1);
    }
    asm volatile("s_waitcnt vmcnt(0)" ::: "memory");
    __syncthreads();
    if (tid==0) astoreu32(&udone[d*32], 1u);

    for (int t=0;t<TMAX;t++){
      const u32 g = (u32)(t+1);
      // --- poll y(g): tagged words, barrier-coupled (r7-stable pattern) ------
      u64 ya, yb;
      for(;;){
        ya = aloadu64(&ytag[2*tid]); yb = aloadu64(&ytag[2*tid+1]);
        const int ok = ((u32)(ya>>32)==g) & ((u32)(yb>>32)==g);
        if (__syncthreads_and(ok)) break;
      }
      SL[zslot(2*tid)]   = __uint_as_float((u32)ya);
      SL[zslot(2*tid+1)] = __uint_as_float((u32)yb);
      __syncthreads();
      float y8[8];
      #pragma unroll
      for (int e=0;e<8;e++) y8[e] = SL[e*64 + (lane ^ (e<<2))];   // y[8*lane+e]
      // --- vp = W_hh @ y partials (off critical path) ---
      float vp[16];
      #pragma unroll
      for (int q=0;q<16;q++){
        float a=0.f;
        #pragma unroll
        for (int k=0;k<8;k++) a = fmaf(whh[q][k], y8[k], a);
        vp[q] = a;
      }
      // --- poll packs(g), barrier-coupled ---
      u64 pk = 0;
      for(;;){
        if (tid < N_CONS) pk = aloadu64(&pkall[(g&3)*224 + tid]);
        const int ok = (tid < N_CONS) ? ((u32)(pk>>48) >= g) : 1;
        if (__syncthreads_and(ok)) break;
      }
      const u64 m = wredmax64(pk);
      if (lane==0) R64[w] = m;
      // speculative embed prefetch of this wave's candidate (direct, no LDS)
      const int predw = (int)((~(u32)m) & 0xFFFFu);
      float e8[8];
      LOAD8(e8, embed + (size_t)predw*EMBED + 8*lane);
      __syncthreads();
      u64 best = R64[0];
      #pragma unroll
      for (int i=1;i<4;i++){ const u64 x=R64[i]; best = (x>best)?x:best; }
      const int pred = (int)((~(u32)best) & 0xFFFFu);
      const int emitted = (pred != 0);
      if (m != best){                            // wave-uniform mispredict: L1-hot reload
        LOAD8(e8, embed + (size_t)pred*EMBED + 8*lane);
      }
      // recycle just-consumed u parity buffer (for epoch g+2): 128 floats/block
      if (tid < 64){
        u64* uz = (u64*)(ubuf + (g&1)*4096 + (d&7)*512) + (d>>3)*64;
        astoreu64(&uz[tid], 0ull);
      }
      // --- gates: in-register wave reductions (no PL transpose) ---
      {
        float a[16];
        #pragma unroll
        for (int q=0;q<16;q++){
          float acc = vp[q];
          #pragma unroll
          for (int k=0;k<8;k++) acc = fmaf(wih[q][k], e8[k], acc);
          a[q] = acc;
        }
        float rs = 0.f;
        #pragma unroll
        for (int q=0;q<16;q++){
          const float s = wredsum(a[q]);
          if (lane==q) rs = s;
        }
        if (lane < 16) GL[w*16 + lane] = rs + bias_l;
      }
      __syncthreads();
      if (tid < 16){
        const float gi=GL[tid], gf=GL[16+tid], gg=GL[32+tid], go=GL[48+tid];
        const float cn = sigmoidf_(gf)*c_st + sigmoidf_(gi)*tanhf(gg);
        const float yn = sigmoidf_(go)*tanhf(cn);
        if (emitted){ c_st = cn; y_st = yn; }
        YO[tid] = y_st;
        if (t < TMAX-1)
          astoreu64(&ytag[16*d + tid], ((u64)(g+1)<<32) | (u64)__float_as_uint(y_st));
      }
      __syncthreads();                           // YO visible to all waves
      if (t < TMAX-1){
        float p0=0.f, p1=0.f;
        #pragma unroll
        for (int k=0;k<16;k++){ p0 = fmaf(wdc0[k], YO[k], p0); p1 = fmaf(wdc1[k], YO[k], p1); }
        float* up = ubuf + ((g+1)&1)*4096 + (d&7)*512;
        atomicAdd(&up[2*tid],   p0);
        atomicAdd(&up[2*tid+1], p1);
      }
      asm volatile("s_waitcnt vmcnt(0)" ::: "memory");
      __syncthreads();
      if (t < TMAX-1 && tid==0) astoreu32(&udone[d*32], g+1);
    }
  }
  // ============================ role: CONSUMER ===============================
  else if (b < AGG_B){
    const int cb = b - CONS0;
    int rowstart, rowcnt;
    if (cb < 188){ rowstart = cb*45;                 rowcnt = 45; }
    else         { rowstart = 8460 + (cb-188)*44;    rowcnt = 44; }
    float wout[12][8];
    #pragma unroll
    for (int q=0;q<12;q++){
      const int s = 12*w + q;
      if (s < rowcnt){
        LOAD8(wout[q], W_out + (size_t)(rowstart+s)*JOINT + lane*8);
      } else {
        #pragma unroll
        for (int k=0;k<8;k++) wout[q][k]=0.f;
      }
    }
    // per-lane row ownership: wave w, lane q<12 -> local row s=12w+q
    const int s12 = 12*w + lane;
    const bool my_val = (lane < 12) && (s12 < rowcnt);
    const int my_row = rowstart + s12;
    const float my_bo = my_val ? b_out[my_row] : 0.f;
    const u32* agrep = &aggr[(cb&7)*32];

    // wait for all hp writers (r1-exact)
    for(;;){
      const int ok = (aloadu32(&done[tid]) == MAGIC);
      if (__syncthreads_and(ok)) break;
    }

    const int j0 = 2*tid, j1 = 2*tid+1;
    const int s0 = zslot(j0), s1 = zslot(j1);
    for (int t=0;t<TMAX;t++){
      const u32 g = (u32)(t+1);
      // prefetch hp pair before the wait
      const float2 h2 = *(const float2*)(hp + (size_t)t*JOINT + j0);
      // --- poll 32 per-block u-done tags (last store fires detection) --------
      for(;;){
        const u32 dv = (tid < N_LSTM) ? aloadu32(&udone[tid*32]) : g;
        if (__syncthreads_and(dv >= g)) break;
      }
      // sum the 8 u replicas for elements j0, j1 (pipelined LLC loads)
      float u0 = 0.f, u1 = 0.f;
      {
        const u64* ub64 = (const u64*)(ubuf + (g&1)*4096) + tid;
        u64 v[8];
        #pragma unroll
        for (int r=0;r<8;r++) v[r] = aloadu64(ub64 + r*256);
        #pragma unroll
        for (int r=0;r<8;r++){
          u0 += __uint_as_float((u32)v[r]);
          u1 += __uint_as_float((u32)(v[r]>>32));
        }
      }
      // prefetch aggregator epoch (non-dependent lead-gate check later)
      u32 agv = 0;
      if (tid==0) agv = aloadu32(agrep);
      SL[s0] = tanhf(h2.x + u0);
      SL[s1] = tanhf(h2.y + u1);
      __syncthreads();
      float z8[8];
      #pragma unroll
      for (int e=0;e<8;e++) z8[e] = SL[e*64 + (lane ^ (e<<2))];   // z[8*lane+e]
      // --- logits: in-register wave reductions (no PL transpose) -------------
      float lg = 0.f;
      {
        float a[12];
        #pragma unroll
        for (int q=0;q<12;q++){
          float acc=0.f;
          #pragma unroll
          for (int k=0;k<8;k++) acc = fmaf(wout[q][k], z8[k], acc);
          a[q] = acc;
        }
        float rs = 0.f;
        #pragma unroll
        for (int q=0;q<12;q++){
          const float s = wredsum(a[q]);
          if (lane==q) rs = s;
        }
        lg = rs + my_bo;
      }
      u64 key = my_val ? (((u64)ordbits(lg)<<16) | (u64)(0xFFFFu & ~(u32)my_row)) : 0;
      const u64 kw = wredmax64(key);
      if (lane==0) R64[w] = kw;
      __syncthreads();
      u64 best = R64[0];
      #pragma unroll
      for (int i=1;i<4;i++){ const u64 x=R64[i]; best = (x>best)?x:best; }
      const float mw = unordbits((u32)(best>>16));
      const float e = my_val ? __expf(lg - mw) : 0.f;
      const float sw = wredsum(e);
      if (lane==0) RF[w] = sw;
      __syncthreads();
      if (tid==0){
        const float S = RF[0]+RF[1]+RF[2]+RF[3];
        // lead-gate: ring depth 4; first check uses prefetched epoch (no RT)
        while ((int)(g - agv) > 3){ __builtin_amdgcn_s_sleep(2); agv = aloadu32(agrep); }
        astoreu64(&saall[(g&3)*224 + cb], ((u64)g<<32) | (u64)__float_as_uint(S));
        astoreu64(&pkall[(g&3)*224 + cb], ((u64)g<<48) | best);
      }
      __syncthreads();   // SL/R64/RF reuse fence
    }
  }
  // ============================ role: AGGREGATOR =============================
  else {
    float score = 0.0f;
    for (int t=0;t<TMAX;t++){
      const u32 g = (u32)(t+1);
      const u64* pks = pkall + (g&3)*224;
      const u64* sas = saall + (g&3)*224;
      u64 pk=0, sa=0;
      for(;;){
        if (tid < N_CONS){ pk = aloadu64(&pks[tid]); sa = aloadu64(&sas[tid]); }
        const int ok = (tid < N_CONS) ? (((u32)(pk>>48)==g) & (((u32)(sa>>32))==g)) : 1;
        if (__syncthreads_and(ok)) break;
      }
      { u64 m = wredmax64(pk); if (lane==0) R64[w]=m; }
      __syncthreads();
      u64 best = R64[0];
      #pragma unroll
      for (int i=1;i<4;i++){ const u64 x=R64[i]; best = (x>best)?x:best; }
      const float mstar = unordbits((u32)(best>>16));
      float term = (tid < N_CONS) ?
        __uint_as_float((u32)sa) * __expf(unordbits((u32)(pk>>16)) - mstar) : 0.f;
      term = wredsum(term);
      if (lane==0) RF[w] = term;
      __syncthreads();
      if (tid==0){
        const float S = RF[0]+RF[1]+RF[2]+RF[3];
        const int pred = (int)((~(u32)best) & 0xFFFFu);
        if (pred != 0) score += -logf(S);
        out[t] = (float)pred;
      }
      __syncthreads();   // protect R64/RF for next iteration
      if (tid < 8) astoreu32(&aggr[tid*32], g);  // publish progress (lead-gate)
    }
    if (tid==0) out[TMAX] = score;
  }
}

extern "C" void kernel_launch(void* const* d_in, const int* in_sizes, int n_in,
                              void* d_out, int out_size, void* d_ws, size_t ws_size,
                              hipStream_t stream)
{
  const float* h     = (const float*)d_in[0];
  const float* embed = (const float*)d_in[1];
  const float* W_ih  = (const float*)d_in[2];
  const float* W_hh  = (const float*)d_in[3];
  const float* b_ih  = (const float*)d_in[4];
  const float* b_hh  = (const float*)d_in[5];
  const float* W_enc = (const float*)d_in[6];
  const float* b_enc = (const float*)d_in[7];
  const float* W_dec = (const float*)d_in[8];
  const float* W_out = (const float*)d_in[9];
  const float* b_out = (const float*)d_in[10];
  float* out = (float*)d_out;
  char* ws = (char*)d_ws;

  hipLaunchKernelGGL(rnnt_init, dim3(32), dim3(NT), 0, stream, ws);
  hipLaunchKernelGGL(rnnt_decode, dim3(NB), dim3(NT), 0, stream,
                     h, embed, W_ih, W_hh, b_ih, b_hh, W_enc, b_enc, W_dec, W_out, b_out,
                     out, ws);
}

// Round 10
// 18494.266 us; speedup vs baseline: 1.1776x; 1.1776x over previous
//
#include <hip/hip_runtime.h>
#include <stdint.h>

typedef unsigned long long u64;
typedef uint32_t u32;

#define NB     256
#define NT     256
#define TMAX   2048
#define EPROJS 1024
#define DUNITS 512
#define EMBED  512
#define JOINT  512
#define ODIM   10000

#define N_LSTM 32          // blocks 0..31: LSTM + tagged partial-u producers
#define CONS0  32          // blocks 32..246: consumers (W_out), 215 blocks
#define N_CONS 215
#define RED0   247         // blocks 247..254: u reducers (8 x 64 elements)
#define AGG_B  255         // block 255: score/token aggregator
#define MAGIC  0xD07ED07Eu

// workspace layout (bytes); first 155648 B zeroed by rnnt_init
// total = 155648 + 4 MB = 4,349,952 B (== r6-proven size, < r3-proven 4,358,144)
#define WS_PK   0          // u64[4][224]   consumer packs, 4-deep ring (tag bits 48+)
#define WS_SA   7168       // u64[4][224]   consumer sum-exp, 4-deep ring (tag bits 32+)
#define WS_DN   14336      // u32[256]      setup-done flags
#define WS_AGG  15360      // u32 aggregator-epoch replicas [8] @ 128B stride
#define WS_Y    16384      // u64[512]      tagged y words (epoch<<32 | f32)
#define WS_U    20480      // u64[512]      tagged u words (epoch<<32 | f32)
#define WS_PART 24576      // u64[32][512]  tagged partial-u words (128 KB)
#define WS_HP   155648     // float[2048][512] h_proj  (4 MB)

__device__ __forceinline__ float aloadf(const float* p){
  return __hip_atomic_load(p, __ATOMIC_RELAXED, __HIP_MEMORY_SCOPE_AGENT);
}
__device__ __forceinline__ void astoref(float* p, float v){
  __hip_atomic_store(p, v, __ATOMIC_RELAXED, __HIP_MEMORY_SCOPE_AGENT);
}
__device__ __forceinline__ u64 aloadu64(const u64* p){
  return __hip_atomic_load(p, __ATOMIC_RELAXED, __HIP_MEMORY_SCOPE_AGENT);
}
__device__ __forceinline__ void astoreu64(u64* p, u64 v){
  __hip_atomic_store(p, v, __ATOMIC_RELAXED, __HIP_MEMORY_SCOPE_AGENT);
}
__device__ __forceinline__ u32 aloadu32(const u32* p){
  return __hip_atomic_load(p, __ATOMIC_RELAXED, __HIP_MEMORY_SCOPE_AGENT);
}
__device__ __forceinline__ void astoreu32(u32* p, u32 v){
  __hip_atomic_store(p, v, __ATOMIC_RELAXED, __HIP_MEMORY_SCOPE_AGENT);
}

__device__ __forceinline__ u32 ordbits(float f){
  u32 u = __float_as_uint(f);
  return (u & 0x80000000u) ? ~u : (u | 0x80000000u);
}
__device__ __forceinline__ float unordbits(u32 o){
  u32 u = (o & 0x80000000u) ? (o & 0x7fffffffu) : ~o;
  return __uint_as_float(u);
}
__device__ __forceinline__ float sigmoidf_(float x){ return 1.0f/(1.0f+expf(-x)); }

__device__ __forceinline__ float wredsum(float v){
  #pragma unroll
  for (int o=32;o>0;o>>=1) v += __shfl_xor(v, o);
  return v;
}
__device__ __forceinline__ u64 wredmax64(u64 v){
  #pragma unroll
  for (int o=32;o>0;o>>=1){ u64 x = __shfl_xor(v, o); v = (x>v)?x:v; }
  return v;
}

// swizzled 512-float LDS stage: j -> (j&7)*64 + ((j>>3) ^ ((j&7)<<2))
// write (j=2tid,2tid+1): <=2-way alias (free); read j=8*lane+e: conflict-free.
__device__ __forceinline__ int zslot(int j){
  return (j&7)*64 + ((j>>3) ^ ((j&7)<<2));
}

#define LOAD8(dst, baseptr) { const float4* _p=(const float4*)(baseptr); \
  float4 _a=_p[0], _b=_p[1]; \
  dst[0]=_a.x; dst[1]=_a.y; dst[2]=_a.z; dst[3]=_a.w; \
  dst[4]=_b.x; dst[5]=_b.y; dst[6]=_b.z; dst[7]=_b.w; }

__global__ void rnnt_init(char* ws){
  // zero rings, flags, agg-epoch, tagged y/u/partials (155648 B = 38912 u32)
  u32* p = (u32*)ws;
  const int stride = blockDim.x * gridDim.x;
  for (int i = blockIdx.x*blockDim.x + threadIdx.x; i < 38912; i += stride) p[i] = 0u;
}

__global__ void __launch_bounds__(NT, 1)
rnnt_decode(const float* __restrict__ h,    const float* __restrict__ embed,
            const float* __restrict__ W_ih, const float* __restrict__ W_hh,
            const float* __restrict__ b_ih, const float* __restrict__ b_hh,
            const float* __restrict__ W_enc,const float* __restrict__ b_enc,
            const float* __restrict__ W_dec,const float* __restrict__ W_out,
            const float* __restrict__ b_out,
            float* __restrict__ out, char* __restrict__ ws)
{
  const int b    = blockIdx.x;
  const int tid  = threadIdx.x;
  const int lane = tid & 63;
  const int w    = tid >> 6;

  u64*   ytag = (u64*)(ws + WS_Y);
  u64*   utag = (u64*)(ws + WS_U);
  u64*   ptag = (u64*)(ws + WS_PART);
  u64*  pkall = (u64*)(ws + WS_PK);
  u64*  saall = (u64*)(ws + WS_SA);
  u32*  done  = (u32*)(ws + WS_DN);
  u32*  aggr  = (u32*)(ws + WS_AGG);
  float* hp   = (float*)(ws + WS_HP);

  __shared__ float smem[8192];                 // 32 KB, multi-purpose
  float* PL = smem;                            // [64][68] partial sums
  float* PS = smem;                            // reducer scratch [4][64]
  float* GL = &smem[4416];                     // gates   (64)
  u64*   R64= (u64*)&smem[4480];               // 4 u64 reduce slots
  float* RF = &smem[4488];                     // 4 float reduce slots
  float* YO = &smem[4492];                     // fresh own-y (16)
  float* SL = &smem[4544];                     // swizzled 512-float stage (y or z)

  // ================= setup: hp = h @ W_enc^T + b_enc (rows 8b..8b+7) =========
  {
    float (*lds_h)[EPROJS] = (float(*)[EPROJS])smem;
    #pragma unroll
    for (int r=0;r<8;r++){
      const float4 hv = *(const float4*)(h + (size_t)(8*b + r)*EPROJS + tid*4);
      *(float4*)&lds_h[r][tid*4] = hv;
    }
    __syncthreads();
    for (int p=0;p<2;p++){
      const int j = p*NT + tid;
      float acc[8] = {0,0,0,0,0,0,0,0};
      const float4* wrow = (const float4*)(W_enc + (size_t)j*EPROJS);
      for (int k4=0;k4<EPROJS/4;k4++){
        const float4 wv = wrow[k4];
        #pragma unroll
        for (int t8=0;t8<8;t8++){
          const float4 hv = *(const float4*)&lds_h[t8][k4*4];
          acc[t8] = fmaf(wv.x,hv.x, fmaf(wv.y,hv.y, fmaf(wv.z,hv.z, fmaf(wv.w,hv.w, acc[t8]))));
        }
      }
      const float be = b_enc[j];
      #pragma unroll
      for (int t8=0;t8<8;t8++)
        astoref(&hp[(size_t)(8*b+t8)*JOINT + j], acc[t8] + be);
    }
    asm volatile("s_waitcnt vmcnt(0)" ::: "memory");
    if (tid==0) astoreu32(&done[b], MAGIC);
    __syncthreads();   // smem reuse fence
  }

  // ============================ role: LSTM ===================================
  if (b < N_LSTM){
    const int d = b;
    float wih[16][8], whh[16][8];
    #pragma unroll
    for (int q=0;q<16;q++){
      const int gr = w*DUNITS + 16*d + q;       // wave w = gate type (i,f,g,o)
      LOAD8(wih[q], W_ih + (size_t)gr*EMBED  + lane*8);
      LOAD8(whh[q], W_hh + (size_t)gr*DUNITS + lane*8);
    }
    // W_dec COLUMN slice: thread owns rows 2tid,2tid+1 x cols [16d,16d+16)
    float wdc0[16], wdc1[16];
    {
      const float4* p0 = (const float4*)(W_dec + (size_t)(2*tid)*DUNITS   + 16*d);
      const float4* p1 = (const float4*)(W_dec + (size_t)(2*tid+1)*DUNITS + 16*d);
      #pragma unroll
      for (int k4=0;k4<4;k4++){
        const float4 a = p0[k4];
        wdc0[4*k4+0]=a.x; wdc0[4*k4+1]=a.y; wdc0[4*k4+2]=a.z; wdc0[4*k4+3]=a.w;
        const float4 c = p1[k4];
        wdc1[4*k4+0]=c.x; wdc1[4*k4+1]=c.y; wdc1[4*k4+2]=c.z; wdc1[4*k4+3]=c.w;
      }
    }
    float bias_r = 0.0f;
    if (tid < 64){
      const int gr = (tid>>4)*DUNITS + 16*d + (tid&15);
      bias_r = b_ih[gr] + b_hh[gr];
    }
    // bootstrap state -> publish tagged y(1) + tagged partial(1)
    float c_st = 0.0f, y_st = 0.0f;
    if (tid < 16){
      const int j = 16*d + tid;
      const float gi = b_ih[j]            + b_hh[j];
      const float gg = b_ih[2*DUNITS + j] + b_hh[2*DUNITS + j];
      const float go = b_ih[3*DUNITS + j] + b_hh[3*DUNITS + j];
      c_st = sigmoidf_(gi)*tanhf(gg);
      y_st = sigmoidf_(go)*tanhf(c_st);
      YO[tid] = y_st;
      astoreu64(&ytag[j], ((u64)1u<<32) | (u64)__float_as_uint(y_st));
    }
    __syncthreads();
    {
      float p0=0.f, p1=0.f;
      #pragma unroll
      for (int k=0;k<16;k++){ p0 = fmaf(wdc0[k], YO[k], p0); p1 = fmaf(wdc1[k], YO[k], p1); }
      u64* up = ptag + (size_t)d*512;
      astoreu64(&up[2*tid],   ((u64)1u<<32) | (u64)__float_as_uint(p0));
      astoreu64(&up[2*tid+1], ((u64)1u<<32) | (u64)__float_as_uint(p1));
    }

    for (int t=0;t<TMAX;t++){
      const u32 g = (u32)(t+1);
      // --- poll y(g): tagged words, barrier-coupled (r7-stable pattern) ------
      u64 ya, yb;
      for(;;){
        ya = aloadu64(&ytag[2*tid]); yb = aloadu64(&ytag[2*tid+1]);
        const int ok = ((u32)(ya>>32)==g) & ((u32)(yb>>32)==g);
        if (__syncthreads_and(ok)) break;
      }
      SL[zslot(2*tid)]   = __uint_as_float((u32)ya);
      SL[zslot(2*tid+1)] = __uint_as_float((u32)yb);
      __syncthreads();
      float y8[8];
      #pragma unroll
      for (int e=0;e<8;e++) y8[e] = SL[e*64 + (lane ^ (e<<2))];   // y[8*lane+e]
      // --- vp = W_hh @ y partials (off critical path) ---
      float vp[16];
      #pragma unroll
      for (int q=0;q<16;q++){
        float a=0.f;
        #pragma unroll
        for (int k=0;k<8;k++) a = fmaf(whh[q][k], y8[k], a);
        vp[q] = a;
      }
      // --- poll packs(g), barrier-coupled ---
      u64 pk = 0;
      for(;;){
        if (tid < N_CONS) pk = aloadu64(&pkall[(g&3)*224 + tid]);
        const int ok = (tid < N_CONS) ? ((u32)(pk>>48) >= g) : 1;
        if (__syncthreads_and(ok)) break;
      }
      const u64 m = wredmax64(pk);
      if (lane==0) R64[w] = m;
      // speculative embed prefetch of this wave's candidate (direct, no LDS)
      const int predw = (int)((~(u32)m) & 0xFFFFu);
      float e8[8];
      LOAD8(e8, embed + (size_t)predw*EMBED + 8*lane);
      __syncthreads();
      u64 best = R64[0];
      #pragma unroll
      for (int i=1;i<4;i++){ const u64 x=R64[i]; best = (x>best)?x:best; }
      const int pred = (int)((~(u32)best) & 0xFFFFu);
      const int emitted = (pred != 0);
      if (m != best){                            // wave-uniform mispredict: L1-hot reload
        LOAD8(e8, embed + (size_t)pred*EMBED + 8*lane);
      }
      // --- gates (r7-exact PL transpose) ---
      #pragma unroll
      for (int q=0;q<16;q++){
        float a = vp[q];
        #pragma unroll
        for (int k=0;k<8;k++) a = fmaf(wih[q][k], e8[k], a);
        PL[(w*16+q)*68 + lane] = a;
      }
      __syncthreads();
      if (tid < 64){
        const float* row = &PL[tid*68];
        float s = bias_r;
        #pragma unroll
        for (int k4=0;k4<16;k4++){
          const float4 v4 = *(const float4*)&row[4*k4];
          s += v4.x + v4.y + v4.z + v4.w;
        }
        GL[tid] = s;
      }
      __syncthreads();
      if (tid < 16){
        const float gi=GL[tid], gf=GL[16+tid], gg=GL[32+tid], go=GL[48+tid];
        const float cn = sigmoidf_(gf)*c_st + sigmoidf_(gi)*tanhf(gg);
        const float yn = sigmoidf_(go)*tanhf(cn);
        if (emitted){ c_st = cn; y_st = yn; }
        YO[tid] = y_st;
        if (t < TMAX-1)
          astoreu64(&ytag[16*d + tid], ((u64)(g+1)<<32) | (u64)__float_as_uint(y_st));
      }
      __syncthreads();                           // YO visible to all waves
      if (t < TMAX-1){
        float p0=0.f, p1=0.f;
        #pragma unroll
        for (int k=0;k<16;k++){ p0 = fmaf(wdc0[k], YO[k], p0); p1 = fmaf(wdc1[k], YO[k], p1); }
        u64* up = ptag + (size_t)d*512;
        astoreu64(&up[2*tid],   ((u64)(g+1)<<32) | (u64)__float_as_uint(p0));
        astoreu64(&up[2*tid+1], ((u64)(g+1)<<32) | (u64)__float_as_uint(p1));
      }
      // next-iteration phase-A barrier fences PL/GL/SL reuse
    }
  }
  // ============================ role: CONSUMER ===============================
  else if (b < RED0){
    const int cb = b - CONS0;                    // 0..214
    int rowstart, rowcnt;
    if (cb < 110){ rowstart = cb*47;                 rowcnt = 47; }
    else         { rowstart = 5170 + (cb-110)*46;    rowcnt = 46; }
    float wout[12][8];
    #pragma unroll
    for (int q=0;q<12;q++){
      const int s = 12*w + q;
      if (s < rowcnt){
        LOAD8(wout[q], W_out + (size_t)(rowstart+s)*JOINT + lane*8);
      } else {
        #pragma unroll
        for (int k=0;k<8;k++) wout[q][k]=0.f;
      }
    }
    float my_bo = 0.f; int my_row = 0; bool my_val = false;
    if (tid < rowcnt){ my_val = true; my_row = rowstart + tid; my_bo = b_out[my_row]; }
    const u32* agrep = &aggr[(cb&7)*32];

    // wait for all hp writers (r1-exact)
    for(;;){
      const int ok = (aloadu32(&done[tid]) == MAGIC);
      if (__syncthreads_and(ok)) break;
    }

    const int j0 = 2*tid, j1 = 2*tid+1;
    const int s0 = zslot(j0), s1 = zslot(j1);
    for (int t=0;t<TMAX;t++){
      const u32 g = (u32)(t+1);
      // prefetch hp pair before the wait
      const float2 h2 = *(const float2*)(hp + (size_t)t*JOINT + j0);
      // --- poll OWN two tagged u words: detect == payload, barrier-coupled ---
      u64 ua, ub2;
      for(;;){
        ua  = aloadu64(&utag[j0]);
        ub2 = aloadu64(&utag[j1]);
        const int ok = (((u32)(ua>>32))>=g) & (((u32)(ub2>>32))>=g);
        if (__syncthreads_and(ok)) break;
      }
      // prefetch aggregator epoch (lead-gate check later is then RT-free)
      u32 agv = 0;
      if (tid==0) agv = aloadu32(agrep);
      SL[s0] = tanhf(h2.x + __uint_as_float((u32)ua));
      SL[s1] = tanhf(h2.y + __uint_as_float((u32)ub2));
      __syncthreads();
      float z8[8];
      #pragma unroll
      for (int e=0;e<8;e++) z8[e] = SL[e*64 + (lane ^ (e<<2))];   // z[8*lane+e]
      #pragma unroll
      for (int q=0;q<12;q++){
        float a=0.f;
        #pragma unroll
        for (int k=0;k<8;k++) a = fmaf(wout[q][k], z8[k], a);
        PL[(12*w+q)*68 + lane] = a;
      }
      __syncthreads();
      u64 key = 0; float lg = 0.f;
      if (tid < 48){
        const float* row = &PL[tid*68];
        float s = my_bo;
        #pragma unroll
        for (int k4=0;k4<16;k4++){
          const float4 v4 = *(const float4*)&row[4*k4];
          s += v4.x + v4.y + v4.z + v4.w;
        }
        lg = s;
        if (my_val) key = ((u64)ordbits(lg)<<16) | (u64)(0xFFFFu & ~(u32)my_row);
      }
      if (w == 0){
        const u64 bk = wredmax64(key);
        const float mw = unordbits((u32)(bk>>16));
        const float e  = my_val ? __expf(lg - mw) : 0.f;
        const float sw = wredsum(e);
        if (lane == 0){
          // lead-gate: ring depth 4; first check uses prefetched epoch (no RT)
          while ((int)(g - agv) > 3){ __builtin_amdgcn_s_sleep(2); agv = aloadu32(agrep); }
          astoreu64(&saall[(g&3)*224 + cb], ((u64)g<<32) | (u64)__float_as_uint(sw));
          astoreu64(&pkall[(g&3)*224 + cb], ((u64)g<<48) | bk);
        }
      }
      __syncthreads();   // PL/SL reuse fence
    }
  }
  // ============================ role: U-REDUCER ==============================
  else if (b < AGG_B){
    const int rr = b - RED0;                     // 0..7
    const int ebase = 64*rr;                     // owns u elements [ebase,ebase+64)
    for (int t=0;t<TMAX;t++){
      const u32 g = (u32)(t+1);
      // wave w covers partials 8w..8w+7, lane = element offset; tag==payload
      u64 pv[8];
      for(;;){
        bool ok = true;
        #pragma unroll
        for (int i=0;i<8;i++){
          pv[i] = aloadu64(&ptag[(size_t)(8*w+i)*512 + ebase + lane]);
          ok &= ((u32)(pv[i]>>32) >= g);
        }
        if (__syncthreads_and(ok)) break;
      }
      float s = 0.f;
      #pragma unroll
      for (int i=0;i<8;i++) s += __uint_as_float((u32)pv[i]);
      PS[w*64 + lane] = s;
      __syncthreads();
      if (tid < 64){
        const float tot = PS[tid] + PS[64+tid] + PS[128+tid] + PS[192+tid];
        astoreu64(&utag[ebase + tid], ((u64)g<<32) | (u64)__float_as_uint(tot));
      }
      // PS reuse at g+1 is fenced by the next poll's barrier (wave 0 enters it
      // only after its PS reads + u publish)
    }
  }
  // ============================ role: AGGREGATOR =============================
  else {
    float score = 0.0f;
    for (int t=0;t<TMAX;t++){
      const u32 g = (u32)(t+1);
      const u64* pks = pkall + (g&3)*224;
      const u64* sas = saall + (g&3)*224;
      u64 pk=0, sa=0;
      for(;;){
        if (tid < N_CONS){ pk = aloadu64(&pks[tid]); sa = aloadu64(&sas[tid]); }
        const int ok = (tid < N_CONS) ? (((u32)(pk>>48)==g) & (((u32)(sa>>32))==g)) : 1;
        if (__syncthreads_and(ok)) break;
      }
      { u64 m = wredmax64(pk); if (lane==0) R64[w]=m; }
      __syncthreads();
      u64 best = R64[0];
      #pragma unroll
      for (int i=1;i<4;i++){ const u64 x=R64[i]; best = (x>best)?x:best; }
      const float mstar = unordbits((u32)(best>>16));
      float term = (tid < N_CONS) ?
        __uint_as_float((u32)sa) * __expf(unordbits((u32)(pk>>16)) - mstar) : 0.f;
      term = wredsum(term);
      if (lane==0) RF[w] = term;
      __syncthreads();
      if (tid==0){
        const float S = RF[0]+RF[1]+RF[2]+RF[3];
        const int pred = (int)((~(u32)best) & 0xFFFFu);
        if (pred != 0) score += -logf(S);
        out[t] = (float)pred;
      }
      __syncthreads();   // protect R64/RF for next iteration
      if (tid < 8) astoreu32(&aggr[tid*32], g);  // publish progress (lead-gate)
    }
    if (tid==0) out[TMAX] = score;
  }
}

extern "C" void kernel_launch(void* const* d_in, const int* in_sizes, int n_in,
                              void* d_out, int out_size, void* d_ws, size_t ws_size,
                              hipStream_t stream)
{
  const float* h     = (const float*)d_in[0];
  const float* embed = (const float*)d_in[1];
  const float* W_ih  = (const float*)d_in[2];
  const float* W_hh  = (const float*)d_in[3];
  const float* b_ih  = (const float*)d_in[4];
  const float* b_hh  = (const float*)d_in[5];
  const float* W_enc = (const float*)d_in[6];
  const float* b_enc = (const float*)d_in[7];
  const float* W_dec = (const float*)d_in[8];
  const float* W_out = (const float*)d_in[9];
  const float* b_out = (const float*)d_in[10];
  float* out = (float*)d_out;
  char* ws = (char*)d_ws;

  hipLaunchKernelGGL(rnnt_init, dim3(32), dim3(NT), 0, stream, ws);
  hipLaunchKernelGGL(rnnt_decode, dim3(NB), dim3(NT), 0, stream,
                     h, embed, W_ih, W_hh, b_ih, b_hh, W_enc, b_enc, W_dec, W_out, b_out,
                     out, ws);
}

// Round 11
// 16406.667 us; speedup vs baseline: 1.3274x; 1.1272x over previous
//
#include <hip/hip_runtime.h>
#include <stdint.h>

typedef unsigned long long u64;
typedef uint32_t u32;

#define NB     256
#define NT     256
#define TMAX   2048
#define EPROJS 1024
#define DUNITS 512
#define EMBED  512
#define JOINT  512
#define ODIM   10000

#define N_LSTM 32          // blocks 0..31: LSTM + replica-atomic u producers
#define CONS0  32          // blocks 32..254: consumers (W_out)
#define N_CONS 223
#define AGG_B  255         // block 255: score/token aggregator
#define MAGIC  0xD07ED07Eu

// workspace layout (bytes); first 54272 B zeroed by rnnt_init
// total = 54272 + 4 MB = 4,248,576 B (r7-proven)
#define WS_PK   0          // u64[4][224]   consumer packs, 4-deep ring (tag bits 48+)
#define WS_SA   7168       // u64[4][224]   consumer sum-exp, 4-deep ring (tag bits 32+)
#define WS_DN   14336      // u32[256]      setup-done flags
#define WS_AGG  15360      // u32 aggregator-epoch replicas [8] @ 128B stride
#define WS_CNT  16384      // u32 u-epoch counter replicas [8] @ 128B stride
#define WS_Y    17408      // u64[512]      tagged y words (epoch<<32 | f32)
#define WS_U    21504      // float[2][8][512] u replicas, parity-2 (32 KB)
#define WS_HP   54272      // float[2048][512] h_proj  (4 MB)

__device__ __forceinline__ float aloadf(const float* p){
  return __hip_atomic_load(p, __ATOMIC_RELAXED, __HIP_MEMORY_SCOPE_AGENT);
}
__device__ __forceinline__ void astoref(float* p, float v){
  __hip_atomic_store(p, v, __ATOMIC_RELAXED, __HIP_MEMORY_SCOPE_AGENT);
}
__device__ __forceinline__ u64 aloadu64(const u64* p){
  return __hip_atomic_load(p, __ATOMIC_RELAXED, __HIP_MEMORY_SCOPE_AGENT);
}
__device__ __forceinline__ void astoreu64(u64* p, u64 v){
  __hip_atomic_store(p, v, __ATOMIC_RELAXED, __HIP_MEMORY_SCOPE_AGENT);
}
__device__ __forceinline__ u32 aloadu32(const u32* p){
  return __hip_atomic_load(p, __ATOMIC_RELAXED, __HIP_MEMORY_SCOPE_AGENT);
}
__device__ __forceinline__ void astoreu32(u32* p, u32 v){
  __hip_atomic_store(p, v, __ATOMIC_RELAXED, __HIP_MEMORY_SCOPE_AGENT);
}

__device__ __forceinline__ u32 ordbits(float f){
  u32 u = __float_as_uint(f);
  return (u & 0x80000000u) ? ~u : (u | 0x80000000u);
}
__device__ __forceinline__ float unordbits(u32 o){
  u32 u = (o & 0x80000000u) ? (o & 0x7fffffffu) : ~o;
  return __uint_as_float(u);
}
__device__ __forceinline__ float sigmoidf_(float x){ return 1.0f/(1.0f+expf(-x)); }

__device__ __forceinline__ float wredsum(float v){
  #pragma unroll
  for (int o=32;o>0;o>>=1) v += __shfl_xor(v, o);
  return v;
}
__device__ __forceinline__ u64 wredmax64(u64 v){
  #pragma unroll
  for (int o=32;o>0;o>>=1){ u64 x = __shfl_xor(v, o); v = (x>v)?x:v; }
  return v;
}

// swizzled 512-float LDS stage: j -> (j&7)*64 + ((j>>3) ^ ((j&7)<<2))
// write (j=2tid,2tid+1): <=2-way alias (free); read j=8*lane+e: conflict-free.
__device__ __forceinline__ int zslot(int j){
  return (j&7)*64 + ((j>>3) ^ ((j&7)<<2));
}

#define LOAD8(dst, baseptr) { const float4* _p=(const float4*)(baseptr); \
  float4 _a=_p[0], _b=_p[1]; \
  dst[0]=_a.x; dst[1]=_a.y; dst[2]=_a.z; dst[3]=_a.w; \
  dst[4]=_b.x; dst[5]=_b.y; dst[6]=_b.z; dst[7]=_b.w; }

__global__ void rnnt_init(char* ws){
  // zero rings, flags, counters, tagged y, u replicas (54272 B = 13568 u32)
  u32* p = (u32*)ws;
  const int stride = blockDim.x * gridDim.x;
  for (int i = blockIdx.x*blockDim.x + threadIdx.x; i < 13568; i += stride) p[i] = 0u;
}

__global__ void __launch_bounds__(NT, 1)
rnnt_decode(const float* __restrict__ h,    const float* __restrict__ embed,
            const float* __restrict__ W_ih, const float* __restrict__ W_hh,
            const float* __restrict__ b_ih, const float* __restrict__ b_hh,
            const float* __restrict__ W_enc,const float* __restrict__ b_enc,
            const float* __restrict__ W_dec,const float* __restrict__ W_out,
            const float* __restrict__ b_out,
            float* __restrict__ out, char* __restrict__ ws)
{
  const int b    = blockIdx.x;
  const int tid  = threadIdx.x;
  const int lane = tid & 63;
  const int w    = tid >> 6;

  u64*   ytag = (u64*)(ws + WS_Y);
  float* ubuf = (float*)(ws + WS_U);      // [2][8][512]
  u64*  pkall = (u64*)(ws + WS_PK);
  u64*  saall = (u64*)(ws + WS_SA);
  u32*  done  = (u32*)(ws + WS_DN);
  u32*  aggr  = (u32*)(ws + WS_AGG);
  u32*  cnt   = (u32*)(ws + WS_CNT);
  float* hp   = (float*)(ws + WS_HP);

  __shared__ float smem[8192];                 // 32 KB, multi-purpose
  float* PL = smem;                            // [64][68] partial sums
  float* GL = &smem[4416];                     // gates   (64)
  u64*   R64= (u64*)&smem[4480];               // 4 u64 reduce slots
  float* RF = &smem[4488];                     // 4 float reduce slots
  float* YO = &smem[4492];                     // fresh own-y (16)
  float* SL = &smem[4544];                     // swizzled 512-float stage (y or z)

  // ================= setup: hp = h @ W_enc^T + b_enc (rows 8b..8b+7) =========
  {
    float (*lds_h)[EPROJS] = (float(*)[EPROJS])smem;
    #pragma unroll
    for (int r=0;r<8;r++){
      const float4 hv = *(const float4*)(h + (size_t)(8*b + r)*EPROJS + tid*4);
      *(float4*)&lds_h[r][tid*4] = hv;
    }
    __syncthreads();
    for (int p=0;p<2;p++){
      const int j = p*NT + tid;
      float acc[8] = {0,0,0,0,0,0,0,0};
      const float4* wrow = (const float4*)(W_enc + (size_t)j*EPROJS);
      for (int k4=0;k4<EPROJS/4;k4++){
        const float4 wv = wrow[k4];
        #pragma unroll
        for (int t8=0;t8<8;t8++){
          const float4 hv = *(const float4*)&lds_h[t8][k4*4];
          acc[t8] = fmaf(wv.x,hv.x, fmaf(wv.y,hv.y, fmaf(wv.z,hv.z, fmaf(wv.w,hv.w, acc[t8]))));
        }
      }
      const float be = b_enc[j];
      #pragma unroll
      for (int t8=0;t8<8;t8++)
        astoref(&hp[(size_t)(8*b+t8)*JOINT + j], acc[t8] + be);
    }
    asm volatile("s_waitcnt vmcnt(0)" ::: "memory");
    if (tid==0) astoreu32(&done[b], MAGIC);
    __syncthreads();   // smem reuse fence
  }

  // ============================ role: LSTM ===================================
  if (b < N_LSTM){
    const int d = b;
    float wih[16][8], whh[16][8];
    #pragma unroll
    for (int q=0;q<16;q++){
      const int gr = w*DUNITS + 16*d + q;       // wave w = gate type (i,f,g,o)
      LOAD8(wih[q], W_ih + (size_t)gr*EMBED  + lane*8);
      LOAD8(whh[q], W_hh + (size_t)gr*DUNITS + lane*8);
    }
    // W_dec COLUMN slice: thread owns rows 2tid,2tid+1 x cols [16d,16d+16)
    float wdc0[16], wdc1[16];
    {
      const float4* p0 = (const float4*)(W_dec + (size_t)(2*tid)*DUNITS   + 16*d);
      const float4* p1 = (const float4*)(W_dec + (size_t)(2*tid+1)*DUNITS + 16*d);
      #pragma unroll
      for (int k4=0;k4<4;k4++){
        const float4 a = p0[k4];
        wdc0[4*k4+0]=a.x; wdc0[4*k4+1]=a.y; wdc0[4*k4+2]=a.z; wdc0[4*k4+3]=a.w;
        const float4 c = p1[k4];
        wdc1[4*k4+0]=c.x; wdc1[4*k4+1]=c.y; wdc1[4*k4+2]=c.z; wdc1[4*k4+3]=c.w;
      }
    }
    float bias_r = 0.0f;
    if (tid < 64){
      const int gr = (tid>>4)*DUNITS + 16*d + (tid&15);
      bias_r = b_ih[gr] + b_hh[gr];
    }
    // bootstrap state -> publish tagged y(1) + replica-add u(1) (parity 1)
    float c_st = 0.0f, y_st = 0.0f;
    if (tid < 16){
      const int j = 16*d + tid;
      const float gi = b_ih[j]            + b_hh[j];
      const float gg = b_ih[2*DUNITS + j] + b_hh[2*DUNITS + j];
      const float go = b_ih[3*DUNITS + j] + b_hh[3*DUNITS + j];
      c_st = sigmoidf_(gi)*tanhf(gg);
      y_st = sigmoidf_(go)*tanhf(c_st);
      YO[tid] = y_st;
      astoreu64(&ytag[j], ((u64)1u<<32) | (u64)__float_as_uint(y_st));
    }
    __syncthreads();
    {
      float p0=0.f, p1=0.f;
      #pragma unroll
      for (int k=0;k<16;k++){ p0 = fmaf(wdc0[k], YO[k], p0); p1 = fmaf(wdc1[k], YO[k], p1); }
      float* up = ubuf + 1*4096 + (d&7)*512;    // parity 1, replica d&7
      atomicAdd(&up[2*tid],   p0);
      atomicAdd(&up[2*tid+1], p1);
    }
    asm volatile("s_waitcnt vmcnt(0)" ::: "memory");
    __syncthreads();
    if (tid < 8) atomicAdd(&cnt[tid*32], 1u);

    for (int t=0;t<TMAX;t++){
      const u32 g = (u32)(t+1);
      // --- poll y(g): tagged words, barrier-coupled (r1-stable pattern) ------
      u64 ya, yb;
      for(;;){
        ya = aloadu64(&ytag[2*tid]); yb = aloadu64(&ytag[2*tid+1]);
        const int ok = ((u32)(ya>>32)==g) & ((u32)(yb>>32)==g);
        if (__syncthreads_and(ok)) break;
      }
      SL[zslot(2*tid)]   = __uint_as_float((u32)ya);
      SL[zslot(2*tid+1)] = __uint_as_float((u32)yb);
      __syncthreads();
      float y8[8];
      #pragma unroll
      for (int e=0;e<8;e++) y8[e] = SL[e*64 + (lane ^ (e<<2))];   // y[8*lane+e]
      // --- vp = W_hh @ y partials (off critical path) ---
      float vp[16];
      #pragma unroll
      for (int q=0;q<16;q++){
        float a=0.f;
        #pragma unroll
        for (int k=0;k<8;k++) a = fmaf(whh[q][k], y8[k], a);
        vp[q] = a;
      }
      // --- poll packs(g), barrier-coupled ---
      u64 pk = 0;
      for(;;){
        if (tid < N_CONS) pk = aloadu64(&pkall[(g&3)*224 + tid]);
        const int ok = (tid < N_CONS) ? ((u32)(pk>>48) >= g) : 1;
        if (__syncthreads_and(ok)) break;
      }
      const u64 m = wredmax64(pk);
      if (lane==0) R64[w] = m;
      // speculative embed prefetch of this wave's candidate (direct, no LDS)
      const int predw = (int)((~(u32)m) & 0xFFFFu);
      float e8[8];
      LOAD8(e8, embed + (size_t)predw*EMBED + 8*lane);
      __syncthreads();
      u64 best = R64[0];
      #pragma unroll
      for (int i=1;i<4;i++){ const u64 x=R64[i]; best = (x>best)?x:best; }
      const int pred = (int)((~(u32)best) & 0xFFFFu);
      const int emitted = (pred != 0);
      if (m != best){                            // wave-uniform mispredict: L1-hot reload
        LOAD8(e8, embed + (size_t)pred*EMBED + 8*lane);
      }
      // recycle just-consumed u parity buffer (for epoch g+2): 128 floats/block
      if (tid < 64){
        u64* uz = (u64*)(ubuf + (g&1)*4096 + (d&7)*512) + (d>>3)*64;
        astoreu64(&uz[tid], 0ull);
      }
      // --- gates ---
      #pragma unroll
      for (int q=0;q<16;q++){
        float a = vp[q];
        #pragma unroll
        for (int k=0;k<8;k++) a = fmaf(wih[q][k], e8[k], a);
        PL[(w*16+q)*68 + lane] = a;
      }
      __syncthreads();
      if (tid < 64){
        const float* row = &PL[tid*68];
        float s = bias_r;
        #pragma unroll
        for (int k4=0;k4<16;k4++){
          const float4 v4 = *(const float4*)&row[4*k4];
          s += v4.x + v4.y + v4.z + v4.w;
        }
        GL[tid] = s;
      }
      __syncthreads();
      if (tid < 16){
        const float gi=GL[tid], gf=GL[16+tid], gg=GL[32+tid], go=GL[48+tid];
        const float cn = sigmoidf_(gf)*c_st + sigmoidf_(gi)*tanhf(gg);
        const float yn = sigmoidf_(go)*tanhf(cn);
        if (emitted){ c_st = cn; y_st = yn; }
        YO[tid] = y_st;
        if (t < TMAX-1)
          astoreu64(&ytag[16*d + tid], ((u64)(g+1)<<32) | (u64)__float_as_uint(y_st));
      }
      __syncthreads();                           // YO visible to all waves
      if (t < TMAX-1){
        float p0=0.f, p1=0.f;
        #pragma unroll
        for (int k=0;k<16;k++){ p0 = fmaf(wdc0[k], YO[k], p0); p1 = fmaf(wdc1[k], YO[k], p1); }
        float* up = ubuf + ((g+1)&1)*4096 + (d&7)*512;
        atomicAdd(&up[2*tid],   p0);
        atomicAdd(&up[2*tid+1], p1);
      }
      asm volatile("s_waitcnt vmcnt(0)" ::: "memory");
      __syncthreads();
      if (t < TMAX-1 && tid < 8) atomicAdd(&cnt[tid*32], 1u);
    }
  }
  // ============================ role: CONSUMER ===============================
  else if (b < AGG_B){
    const int cb = b - CONS0;
    int rowstart, rowcnt;
    if (cb < 188){ rowstart = cb*45;                 rowcnt = 45; }
    else         { rowstart = 8460 + (cb-188)*44;    rowcnt = 44; }
    float wout[12][8];
    #pragma unroll
    for (int q=0;q<12;q++){
      const int s = 12*w + q;
      if (s < rowcnt){
        LOAD8(wout[q], W_out + (size_t)(rowstart+s)*JOINT + lane*8);
      } else {
        #pragma unroll
        for (int k=0;k<8;k++) wout[q][k]=0.f;
      }
    }
    float my_bo = 0.f; int my_row = 0; bool my_val = false;
    if (tid < rowcnt){ my_val = true; my_row = rowstart + tid; my_bo = b_out[my_row]; }
    const u32* agrep = &aggr[(cb&7)*32];

    // wait for all hp writers (r1-exact)
    for(;;){
      const int ok = (aloadu32(&done[tid]) == MAGIC);
      if (__syncthreads_and(ok)) break;
    }

    const u32* cp = &cnt[(cb&7)*32];
    const int j0 = 2*tid, j1 = 2*tid+1;
    const int s0 = zslot(j0), s1 = zslot(j1);
    for (int t=0;t<TMAX;t++){
      const u32 g = (u32)(t+1);
      // prefetch hp pair before the wait
      const float2 h2 = *(const float2*)(hp + (size_t)t*JOINT + j0);
      if (tid==0){ while (aloadu32(cp) < 32u*g) {} }
      __syncthreads();
      // sum the 8 u replicas for elements j0, j1 (pipelined LLC loads)
      float u0 = 0.f, u1 = 0.f;
      {
        const u64* ub64 = (const u64*)(ubuf + (g&1)*4096) + tid;
        u64 v[8];
        #pragma unroll
        for (int r=0;r<8;r++) v[r] = aloadu64(ub64 + r*256);
        #pragma unroll
        for (int r=0;r<8;r++){
          u0 += __uint_as_float((u32)v[r]);
          u1 += __uint_as_float((u32)(v[r]>>32));
        }
      }
      // lead-gate epoch prefetch: overlaps with tanh/W_out compute below, so
      // the publish-path check is RT-free (r7 did a dependent load there)
      u32 agv = 0;
      if (tid==0) agv = aloadu32(agrep);
      SL[s0] = tanhf(h2.x + u0);
      SL[s1] = tanhf(h2.y + u1);
      __syncthreads();
      float z8[8];
      #pragma unroll
      for (int e=0;e<8;e++) z8[e] = SL[e*64 + (lane ^ (e<<2))];   // z[8*lane+e]
      #pragma unroll
      for (int q=0;q<12;q++){
        float a=0.f;
        #pragma unroll
        for (int k=0;k<8;k++) a = fmaf(wout[q][k], z8[k], a);
        PL[(12*w+q)*68 + lane] = a;
      }
      __syncthreads();
      u64 key = 0; float lg = 0.f;
      if (tid < 48){
        const float* row = &PL[tid*68];
        float s = my_bo;
        #pragma unroll
        for (int k4=0;k4<16;k4++){
          const float4 v4 = *(const float4*)&row[4*k4];
          s += v4.x + v4.y + v4.z + v4.w;
        }
        lg = s;
        if (my_val) key = ((u64)ordbits(lg)<<16) | (u64)(0xFFFFu & ~(u32)my_row);
      }
      if (w == 0){
        const u64 bk = wredmax64(key);
        const float mw = unordbits((u32)(bk>>16));
        const float e  = my_val ? __expf(lg - mw) : 0.f;
        const float sw = wredsum(e);
        if (lane == 0){
          // lead-gate: ring depth 4; first check uses prefetched epoch (no RT)
          while ((int)(g - agv) > 3){ __builtin_amdgcn_s_sleep(2); agv = aloadu32(agrep); }
          astoreu64(&saall[(g&3)*224 + cb], ((u64)g<<32) | (u64)__float_as_uint(sw));
          astoreu64(&pkall[(g&3)*224 + cb], ((u64)g<<48) | bk);
        }
      }
      __syncthreads();   // PL/SL reuse fence
    }
  }
  // ============================ role: AGGREGATOR =============================
  else {
    float score = 0.0f;
    for (int t=0;t<TMAX;t++){
      const u32 g = (u32)(t+1);
      const u64* pks = pkall + (g&3)*224;
      const u64* sas = saall + (g&3)*224;
      u64 pk=0, sa=0;
      for(;;){
        if (tid < N_CONS){ pk = aloadu64(&pks[tid]); sa = aloadu64(&sas[tid]); }
        const int ok = (tid < N_CONS) ? (((u32)(pk>>48)==g) & (((u32)(sa>>32))==g)) : 1;
        if (__syncthreads_and(ok)) break;
      }
      { u64 m = wredmax64(pk); if (lane==0) R64[w]=m; }
      __syncthreads();
      u64 best = R64[0];
      #pragma unroll
      for (int i=1;i<4;i++){ const u64 x=R64[i]; best = (x>best)?x:best; }
      const float mstar = unordbits((u32)(best>>16));
      float term = (tid < N_CONS) ?
        __uint_as_float((u32)sa) * __expf(unordbits((u32)(pk>>16)) - mstar) : 0.f;
      term = wredsum(term);
      if (lane==0) RF[w] = term;
      __syncthreads();
      if (tid==0){
        const float S = RF[0]+RF[1]+RF[2]+RF[3];
        const int pred = (int)((~(u32)best) & 0xFFFFu);
        if (pred != 0) score += -logf(S);
        out[t] = (float)pred;
      }
      __syncthreads();   // protect R64/RF for next iteration
      if (tid < 8) astoreu32(&aggr[tid*32], g);  // publish progress (lead-gate)
    }
    if (tid==0) out[TMAX] = score;
  }
}

extern "C" void kernel_launch(void* const* d_in, const int* in_sizes, int n_in,
                              void* d_out, int out_size, void* d_ws, size_t ws_size,
                              hipStream_t stream)
{
  const float* h     = (const float*)d_in[0];
  const float* embed = (const float*)d_in[1];
  const float* W_ih  = (const float*)d_in[2];
  const float* W_hh  = (const float*)d_in[3];
  const float* b_ih  = (const float*)d_in[4];
  const float* b_hh  = (const float*)d_in[5];
  const float* W_enc = (const float*)d_in[6];
  const float* b_enc = (const float*)d_in[7];
  const float* W_dec = (const float*)d_in[8];
  const float* W_out = (const float*)d_in[9];
  const float* b_out = (const float*)d_in[10];
  float* out = (float*)d_out;
  char* ws = (char*)d_ws;

  hipLaunchKernelGGL(rnnt_init, dim3(32), dim3(NT), 0, stream, ws);
  hipLaunchKernelGGL(rnnt_decode, dim3(NB), dim3(NT), 0, stream,
                     h, embed, W_ih, W_hh, b_ih, b_hh, W_enc, b_enc, W_dec, W_out, b_out,
                     out, ws);
}

// Round 12
// 16285.733 us; speedup vs baseline: 1.3373x; 1.0074x over previous
//
#include <hip/hip_runtime.h>
#include <stdint.h>

typedef unsigned long long u64;
typedef uint32_t u32;

#define NB     256
#define NT     256
#define TMAX   2048
#define EPROJS 1024
#define DUNITS 512
#define EMBED  512
#define JOINT  512
#define ODIM   10000

#define N_LSTM 32          // blocks 0..31: LSTM + replica-atomic u producers
#define CONS0  32          // blocks 32..254: consumers (W_out)
#define N_CONS 223
#define AGG_B  255         // block 255: score/token aggregator
#define MAGIC  0xD07ED07Eu

// workspace layout (bytes); first 54272 B zeroed by rnnt_init
// total = 54272 + 4 MB = 4,248,576 B (r7-proven)
#define WS_PK   0          // u64[4][224]   consumer packs, 4-deep ring (tag bits 48+)
#define WS_SA   7168       // u64[4][224]   consumer sum-exp, 4-deep ring (tag bits 32+)
#define WS_DN   14336      // u32[256]      setup-done flags
#define WS_AGG  15360      // u32 aggregator-epoch replicas [8] @ 128B stride
#define WS_CNT  16384      // u32 u-epoch counter replicas [8] @ 128B stride
#define WS_Y    17408      // u64[512]      tagged y words (epoch<<32 | f32)
#define WS_U    21504      // float[2][8][512] u replicas, parity-2 (32 KB)
#define WS_HP   54272      // float[2048][512] h_proj  (4 MB)

__device__ __forceinline__ float aloadf(const float* p){
  return __hip_atomic_load(p, __ATOMIC_RELAXED, __HIP_MEMORY_SCOPE_AGENT);
}
__device__ __forceinline__ void astoref(float* p, float v){
  __hip_atomic_store(p, v, __ATOMIC_RELAXED, __HIP_MEMORY_SCOPE_AGENT);
}
__device__ __forceinline__ u64 aloadu64(const u64* p){
  return __hip_atomic_load(p, __ATOMIC_RELAXED, __HIP_MEMORY_SCOPE_AGENT);
}
__device__ __forceinline__ void astoreu64(u64* p, u64 v){
  __hip_atomic_store(p, v, __ATOMIC_RELAXED, __HIP_MEMORY_SCOPE_AGENT);
}
__device__ __forceinline__ u32 aloadu32(const u32* p){
  return __hip_atomic_load(p, __ATOMIC_RELAXED, __HIP_MEMORY_SCOPE_AGENT);
}
__device__ __forceinline__ void astoreu32(u32* p, u32 v){
  __hip_atomic_store(p, v, __ATOMIC_RELAXED, __HIP_MEMORY_SCOPE_AGENT);
}

__device__ __forceinline__ u32 ordbits(float f){
  u32 u = __float_as_uint(f);
  return (u & 0x80000000u) ? ~u : (u | 0x80000000u);
}
__device__ __forceinline__ float unordbits(u32 o){
  u32 u = (o & 0x80000000u) ? (o & 0x7fffffffu) : ~o;
  return __uint_as_float(u);
}
__device__ __forceinline__ float sigmoidf_(float x){ return 1.0f/(1.0f+expf(-x)); }

__device__ __forceinline__ float wredsum(float v){
  #pragma unroll
  for (int o=32;o>0;o>>=1) v += __shfl_xor(v, o);
  return v;
}
__device__ __forceinline__ u64 wredmax64(u64 v){
  #pragma unroll
  for (int o=32;o>0;o>>=1){ u64 x = __shfl_xor(v, o); v = (x>v)?x:v; }
  return v;
}

// swizzled 512-float LDS stage: j -> (j&7)*64 + ((j>>3) ^ ((j&7)<<2))
// write (j=2tid,2tid+1): <=2-way alias (free); read j=8*lane+e: conflict-free.
__device__ __forceinline__ int zslot(int j){
  return (j&7)*64 + ((j>>3) ^ ((j&7)<<2));
}

#define LOAD8(dst, baseptr) { const float4* _p=(const float4*)(baseptr); \
  float4 _a=_p[0], _b=_p[1]; \
  dst[0]=_a.x; dst[1]=_a.y; dst[2]=_a.z; dst[3]=_a.w; \
  dst[4]=_b.x; dst[5]=_b.y; dst[6]=_b.z; dst[7]=_b.w; }

__global__ void rnnt_init(char* ws){
  // zero rings, flags, counters, tagged y, u replicas (54272 B = 13568 u32)
  u32* p = (u32*)ws;
  const int stride = blockDim.x * gridDim.x;
  for (int i = blockIdx.x*blockDim.x + threadIdx.x; i < 13568; i += stride) p[i] = 0u;
}

__global__ void __launch_bounds__(NT, 1)
rnnt_decode(const float* __restrict__ h,    const float* __restrict__ embed,
            const float* __restrict__ W_ih, const float* __restrict__ W_hh,
            const float* __restrict__ b_ih, const float* __restrict__ b_hh,
            const float* __restrict__ W_enc,const float* __restrict__ b_enc,
            const float* __restrict__ W_dec,const float* __restrict__ W_out,
            const float* __restrict__ b_out,
            float* __restrict__ out, char* __restrict__ ws)
{
  const int b    = blockIdx.x;
  const int tid  = threadIdx.x;
  const int lane = tid & 63;
  const int w    = tid >> 6;

  u64*   ytag = (u64*)(ws + WS_Y);
  float* ubuf = (float*)(ws + WS_U);      // [2][8][512]
  u64*  pkall = (u64*)(ws + WS_PK);
  u64*  saall = (u64*)(ws + WS_SA);
  u32*  done  = (u32*)(ws + WS_DN);
  u32*  aggr  = (u32*)(ws + WS_AGG);
  u32*  cnt   = (u32*)(ws + WS_CNT);
  float* hp   = (float*)(ws + WS_HP);

  __shared__ float smem[8192];                 // 32 KB, multi-purpose
  float* PL = smem;                            // [64][68] partial sums
  float* GL = &smem[4416];                     // gates   (64)
  u64*   R64= (u64*)&smem[4480];               // 4 u64 reduce slots
  float* RF = &smem[4488];                     // 4 float reduce slots
  float* YO = &smem[4492];                     // fresh own-y (16)
  float* SL = &smem[4544];                     // swizzled 512-float stage (z)

  // ================= setup: hp = h @ W_enc^T + b_enc (rows 8b..8b+7) =========
  {
    float (*lds_h)[EPROJS] = (float(*)[EPROJS])smem;
    #pragma unroll
    for (int r=0;r<8;r++){
      const float4 hv = *(const float4*)(h + (size_t)(8*b + r)*EPROJS + tid*4);
      *(float4*)&lds_h[r][tid*4] = hv;
    }
    __syncthreads();
    for (int p=0;p<2;p++){
      const int j = p*NT + tid;
      float acc[8] = {0,0,0,0,0,0,0,0};
      const float4* wrow = (const float4*)(W_enc + (size_t)j*EPROJS);
      for (int k4=0;k4<EPROJS/4;k4++){
        const float4 wv = wrow[k4];
        #pragma unroll
        for (int t8=0;t8<8;t8++){
          const float4 hv = *(const float4*)&lds_h[t8][k4*4];
          acc[t8] = fmaf(wv.x,hv.x, fmaf(wv.y,hv.y, fmaf(wv.z,hv.z, fmaf(wv.w,hv.w, acc[t8]))));
        }
      }
      const float be = b_enc[j];
      #pragma unroll
      for (int t8=0;t8<8;t8++)
        astoref(&hp[(size_t)(8*b+t8)*JOINT + j], acc[t8] + be);
    }
    asm volatile("s_waitcnt vmcnt(0)" ::: "memory");
    if (tid==0) astoreu32(&done[b], MAGIC);
    __syncthreads();   // smem reuse fence
  }

  // ============================ role: LSTM ===================================
  if (b < N_LSTM){
    const int d = b;
    float wih[16][8], whh[16][8];
    #pragma unroll
    for (int q=0;q<16;q++){
      const int gr = w*DUNITS + 16*d + q;       // wave w = gate type (i,f,g,o)
      LOAD8(wih[q], W_ih + (size_t)gr*EMBED  + lane*8);
      LOAD8(whh[q], W_hh + (size_t)gr*DUNITS + lane*8);
    }
    // W_dec COLUMN slice: thread owns rows 2tid,2tid+1 x cols [16d,16d+16)
    float wdc0[16], wdc1[16];
    {
      const float4* p0 = (const float4*)(W_dec + (size_t)(2*tid)*DUNITS   + 16*d);
      const float4* p1 = (const float4*)(W_dec + (size_t)(2*tid+1)*DUNITS + 16*d);
      #pragma unroll
      for (int k4=0;k4<4;k4++){
        const float4 a = p0[k4];
        wdc0[4*k4+0]=a.x; wdc0[4*k4+1]=a.y; wdc0[4*k4+2]=a.z; wdc0[4*k4+3]=a.w;
        const float4 c = p1[k4];
        wdc1[4*k4+0]=c.x; wdc1[4*k4+1]=c.y; wdc1[4*k4+2]=c.z; wdc1[4*k4+3]=c.w;
      }
    }
    float bias_r = 0.0f;
    if (tid < 64){
      const int gr = (tid>>4)*DUNITS + 16*d + (tid&15);
      bias_r = b_ih[gr] + b_hh[gr];
    }
    // bootstrap state -> publish tagged y(1) + replica-add u(1) (parity 1)
    float c_st = 0.0f, y_st = 0.0f;
    if (tid < 16){
      const int j = 16*d + tid;
      const float gi = b_ih[j]            + b_hh[j];
      const float gg = b_ih[2*DUNITS + j] + b_hh[2*DUNITS + j];
      const float go = b_ih[3*DUNITS + j] + b_hh[3*DUNITS + j];
      c_st = sigmoidf_(gi)*tanhf(gg);
      y_st = sigmoidf_(go)*tanhf(c_st);
      YO[tid] = y_st;
      astoreu64(&ytag[j], ((u64)1u<<32) | (u64)__float_as_uint(y_st));
    }
    __syncthreads();
    {
      float p0=0.f, p1=0.f;
      #pragma unroll
      for (int k=0;k<16;k++){ p0 = fmaf(wdc0[k], YO[k], p0); p1 = fmaf(wdc1[k], YO[k], p1); }
      float* up = ubuf + 1*4096 + (d&7)*512;    // parity 1, replica d&7
      atomicAdd(&up[2*tid],   p0);
      atomicAdd(&up[2*tid+1], p1);
    }
    asm volatile("s_waitcnt vmcnt(0)" ::: "memory");
    __syncthreads();
    if (tid < 8) atomicAdd(&cnt[tid*32], 1u);

    for (int t=0;t<TMAX;t++){
      const u32 g = (u32)(t+1);
      // --- poll y(g): each thread polls the 8 words IT consumes --------------
      // (payload==detect; barrier-coupled; y8 is in registers on poll exit.
      //  replaces r11's poll + SL stage + extra barrier)
      u64 yv[8];
      for(;;){
        bool ok = true;
        #pragma unroll
        for (int i=0;i<8;i++){
          yv[i] = aloadu64(&ytag[8*lane + i]);
          ok &= ((u32)(yv[i]>>32) == g);
        }
        if (__syncthreads_and(ok)) break;
      }
      float y8[8];
      #pragma unroll
      for (int i=0;i<8;i++) y8[i] = __uint_as_float((u32)yv[i]);
      // --- vp = W_hh @ y partials (off critical path) ---
      float vp[16];
      #pragma unroll
      for (int q=0;q<16;q++){
        float a=0.f;
        #pragma unroll
        for (int k=0;k<8;k++) a = fmaf(whh[q][k], y8[k], a);
        vp[q] = a;
      }
      // --- poll packs(g), barrier-coupled ---
      u64 pk = 0;
      for(;;){
        if (tid < N_CONS) pk = aloadu64(&pkall[(g&3)*224 + tid]);
        const int ok = (tid < N_CONS) ? ((u32)(pk>>48) >= g) : 1;
        if (__syncthreads_and(ok)) break;
      }
      const u64 m = wredmax64(pk);
      if (lane==0) R64[w] = m;
      // speculative embed prefetch of this wave's candidate (direct, no LDS)
      const int predw = (int)((~(u32)m) & 0xFFFFu);
      float e8[8];
      LOAD8(e8, embed + (size_t)predw*EMBED + 8*lane);
      __syncthreads();
      u64 best = R64[0];
      #pragma unroll
      for (int i=1;i<4;i++){ const u64 x=R64[i]; best = (x>best)?x:best; }
      const int pred = (int)((~(u32)best) & 0xFFFFu);
      const int emitted = (pred != 0);
      if (m != best){                            // wave-uniform mispredict: L1-hot reload
        LOAD8(e8, embed + (size_t)pred*EMBED + 8*lane);
      }
      // recycle just-consumed u parity buffer (for epoch g+2): 128 floats/block
      if (tid < 64){
        u64* uz = (u64*)(ubuf + (g&1)*4096 + (d&7)*512) + (d>>3)*64;
        astoreu64(&uz[tid], 0ull);
      }
      // --- gates ---
      #pragma unroll
      for (int q=0;q<16;q++){
        float a = vp[q];
        #pragma unroll
        for (int k=0;k<8;k++) a = fmaf(wih[q][k], e8[k], a);
        PL[(w*16+q)*68 + lane] = a;
      }
      __syncthreads();
      if (tid < 64){
        const float* row = &PL[tid*68];
        float s = bias_r;
        #pragma unroll
        for (int k4=0;k4<16;k4++){
          const float4 v4 = *(const float4*)&row[4*k4];
          s += v4.x + v4.y + v4.z + v4.w;
        }
        GL[tid] = s;
      }
      __syncthreads();
      if (tid < 16){
        const float gi=GL[tid], gf=GL[16+tid], gg=GL[32+tid], go=GL[48+tid];
        const float cn = sigmoidf_(gf)*c_st + sigmoidf_(gi)*tanhf(gg);
        const float yn = sigmoidf_(go)*tanhf(cn);
        if (emitted){ c_st = cn; y_st = yn; }
        YO[tid] = y_st;
        if (t < TMAX-1)
          astoreu64(&ytag[16*d + tid], ((u64)(g+1)<<32) | (u64)__float_as_uint(y_st));
      }
      __syncthreads();                           // YO visible to all waves
      if (t < TMAX-1){
        float p0=0.f, p1=0.f;
        #pragma unroll
        for (int k=0;k<16;k++){ p0 = fmaf(wdc0[k], YO[k], p0); p1 = fmaf(wdc1[k], YO[k], p1); }
        float* up = ubuf + ((g+1)&1)*4096 + (d&7)*512;
        atomicAdd(&up[2*tid],   p0);
        atomicAdd(&up[2*tid+1], p1);
      }
      asm volatile("s_waitcnt vmcnt(0)" ::: "memory");
      __syncthreads();
      if (t < TMAX-1 && tid < 8) atomicAdd(&cnt[tid*32], 1u);
    }
  }
  // ============================ role: CONSUMER ===============================
  else if (b < AGG_B){
    const int cb = b - CONS0;
    int rowstart, rowcnt;
    if (cb < 188){ rowstart = cb*45;                 rowcnt = 45; }
    else         { rowstart = 8460 + (cb-188)*44;    rowcnt = 44; }
    float wout[12][8];
    #pragma unroll
    for (int q=0;q<12;q++){
      const int s = 12*w + q;
      if (s < rowcnt){
        LOAD8(wout[q], W_out + (size_t)(rowstart+s)*JOINT + lane*8);
      } else {
        #pragma unroll
        for (int k=0;k<8;k++) wout[q][k]=0.f;
      }
    }
    float my_bo = 0.f; int my_row = 0; bool my_val = false;
    if (tid < rowcnt){ my_val = true; my_row = rowstart + tid; my_bo = b_out[my_row]; }
    const u32* agrep = &aggr[(cb&7)*32];

    // wait for all hp writers (r1-exact)
    for(;;){
      const int ok = (aloadu32(&done[tid]) == MAGIC);
      if (__syncthreads_and(ok)) break;
    }

    const u32* cp = &cnt[(cb&7)*32];
    const int j0 = 2*tid, j1 = 2*tid+1;
    const int s0 = zslot(j0), s1 = zslot(j1);
    for (int t=0;t<TMAX;t++){
      const u32 g = (u32)(t+1);
      // prefetch hp pair before the wait
      const float2 h2 = *(const float2*)(hp + (size_t)t*JOINT + j0);
      if (tid==0){ while (aloadu32(cp) < 32u*g) {} }
      __syncthreads();
      // sum the 8 u replicas for elements j0, j1 (pipelined LLC loads)
      float u0 = 0.f, u1 = 0.f;
      {
        const u64* ub64 = (const u64*)(ubuf + (g&1)*4096) + tid;
        u64 v[8];
        #pragma unroll
        for (int r=0;r<8;r++) v[r] = aloadu64(ub64 + r*256);
        #pragma unroll
        for (int r=0;r<8;r++){
          u0 += __uint_as_float((u32)v[r]);
          u1 += __uint_as_float((u32)(v[r]>>32));
        }
      }
      // lead-gate epoch prefetch: overlaps with tanh/W_out compute below, so
      // the publish-path check is RT-free
      u32 agv = 0;
      if (tid==0) agv = aloadu32(agrep);
      SL[s0] = tanhf(h2.x + u0);
      SL[s1] = tanhf(h2.y + u1);
      __syncthreads();
      float z8[8];
      #pragma unroll
      for (int e=0;e<8;e++) z8[e] = SL[e*64 + (lane ^ (e<<2))];   // z[8*lane+e]
      #pragma unroll
      for (int q=0;q<12;q++){
        float a=0.f;
        #pragma unroll
        for (int k=0;k<8;k++) a = fmaf(wout[q][k], z8[k], a);
        PL[(12*w+q)*68 + lane] = a;
      }
      __syncthreads();
      u64 key = 0; float lg = 0.f;
      if (tid < 48){
        const float* row = &PL[tid*68];
        float s = my_bo;
        #pragma unroll
        for (int k4=0;k4<16;k4++){
          const float4 v4 = *(const float4*)&row[4*k4];
          s += v4.x + v4.y + v4.z + v4.w;
        }
        lg = s;
        if (my_val) key = ((u64)ordbits(lg)<<16) | (u64)(0xFFFFu & ~(u32)my_row);
      }
      if (w == 0){
        const u64 bk = wredmax64(key);
        const float mw = unordbits((u32)(bk>>16));
        const float e  = my_val ? __expf(lg - mw) : 0.f;
        const float sw = wredsum(e);
        if (lane == 0){
          // lead-gate: ring depth 4; first check uses prefetched epoch (no RT)
          while ((int)(g - agv) > 3){ __builtin_amdgcn_s_sleep(2); agv = aloadu32(agrep); }
          astoreu64(&saall[(g&3)*224 + cb], ((u64)g<<32) | (u64)__float_as_uint(sw));
          astoreu64(&pkall[(g&3)*224 + cb], ((u64)g<<48) | bk);
        }
      }
      __syncthreads();   // PL/SL reuse fence
    }
  }
  // ============================ role: AGGREGATOR =============================
  else {
    float score = 0.0f;
    for (int t=0;t<TMAX;t++){
      const u32 g = (u32)(t+1);
      const u64* pks = pkall + (g&3)*224;
      const u64* sas = saall + (g&3)*224;
      u64 pk=0, sa=0;
      for(;;){
        if (tid < N_CONS){ pk = aloadu64(&pks[tid]); sa = aloadu64(&sas[tid]); }
        const int ok = (tid < N_CONS) ? (((u32)(pk>>48)==g) & (((u32)(sa>>32))==g)) : 1;
        if (__syncthreads_and(ok)) break;
      }
      { u64 m = wredmax64(pk); if (lane==0) R64[w]=m; }
      __syncthreads();
      u64 best = R64[0];
      #pragma unroll
      for (int i=1;i<4;i++){ const u64 x=R64[i]; best = (x>best)?x:best; }
      const float mstar = unordbits((u32)(best>>16));
      float term = (tid < N_CONS) ?
        __uint_as_float((u32)sa) * __expf(unordbits((u32)(pk>>16)) - mstar) : 0.f;
      term = wredsum(term);
      if (lane==0) RF[w] = term;
      __syncthreads();
      if (tid==0){
        const float S = RF[0]+RF[1]+RF[2]+RF[3];
        const int pred = (int)((~(u32)best) & 0xFFFFu);
        if (pred != 0) score += -logf(S);
        out[t] = (float)pred;
      }
      __syncthreads();   // protect R64/RF for next iteration
      if (tid < 8) astoreu32(&aggr[tid*32], g);  // publish progress (lead-gate)
    }
    if (tid==0) out[TMAX] = score;
  }
}

extern "C" void kernel_launch(void* const* d_in, const int* in_sizes, int n_in,
                              void* d_out, int out_size, void* d_ws, size_t ws_size,
                              hipStream_t stream)
{
  const float* h     = (const float*)d_in[0];
  const float* embed = (const float*)d_in[1];
  const float* W_ih  = (const float*)d_in[2];
  const float* W_hh  = (const float*)d_in[3];
  const float* b_ih  = (const float*)d_in[4];
  const float* b_hh  = (const float*)d_in[5];
  const float* W_enc = (const float*)d_in[6];
  const float* b_enc = (const float*)d_in[7];
  const float* W_dec = (const float*)d_in[8];
  const float* W_out = (const float*)d_in[9];
  const float* b_out = (const float*)d_in[10];
  float* out = (float*)d_out;
  char* ws = (char*)d_ws;

  hipLaunchKernelGGL(rnnt_init, dim3(32), dim3(NT), 0, stream, ws);
  hipLaunchKernelGGL(rnnt_decode, dim3(NB), dim3(NT), 0, stream,
                     h, embed, W_ih, W_hh, b_ih, b_hh, W_enc, b_enc, W_dec, W_out, b_out,
                     out, ws);
}